// Round 1
// baseline (1043.662 us; speedup 1.0000x reference)
//
#include <hip/hip_runtime.h>

#define B 8
#define C 256
#define L 2048
#define CQK 32
#define TI 16

// ---------------------------------------------------------------------------
// ws layout (floats):
//   qt[b][l][CQK]  : B*L*CQK   (q transposed: column i contiguous)
//   kk[b][c][l]    : B*CQK*L   (k natural: coalesced over j)
//   vt[b][l][C]    : B*L*C     (v transposed: coalesced over c in PV)
// total = 2 MB + 2 MB + 16 MB = 20 MB
// ---------------------------------------------------------------------------

__global__ __launch_bounds__(256) void qk_proj(
    const float* __restrict__ x, const float* __restrict__ Wq,
    const float* __restrict__ bq, const float* __restrict__ Wk,
    const float* __restrict__ bk, float* __restrict__ qt,
    float* __restrict__ kk)
{
    const int b = blockIdx.x;
    const int l = blockIdx.y * 256 + threadIdx.x;
    const float* xb = x + ((size_t)b * C) * L + l;

    float accq[CQK], acck[CQK];
#pragma unroll
    for (int o = 0; o < CQK; o++) { accq[o] = bq[o]; acck[o] = bk[o]; }

#pragma unroll 1
    for (int c0 = 0; c0 < C; c0 += 8) {
        float xr[8];
#pragma unroll
        for (int cc = 0; cc < 8; cc++) xr[cc] = xb[(size_t)(c0 + cc) * L];
#pragma unroll
        for (int o = 0; o < CQK; o++) {
#pragma unroll
            for (int cc = 0; cc < 8; cc++) {
                accq[o] = fmaf(Wq[o * C + c0 + cc], xr[cc], accq[o]);
                acck[o] = fmaf(Wk[o * C + c0 + cc], xr[cc], acck[o]);
            }
        }
    }
    float* qp = qt + ((size_t)b * L + l) * CQK;
#pragma unroll
    for (int o = 0; o < CQK; o++) qp[o] = accq[o];
    float* kp = kk + ((size_t)b * CQK) * L + l;
#pragma unroll
    for (int o = 0; o < CQK; o++) kp[(size_t)o * L] = acck[o];
}

__global__ __launch_bounds__(256) void v_proj(
    const float* __restrict__ x, const float* __restrict__ Wv,
    const float* __restrict__ bv, float* __restrict__ vt)
{
    const int b = blockIdx.x;
    const int lane = threadIdx.x & 63;
    const int og = threadIdx.x >> 6;   // 4 groups of 64 out-channels
    const int l = blockIdx.y * 64 + lane;
    const float* xb = x + ((size_t)b * C) * L + l;
    const float* W = Wv + (size_t)og * 64 * C;

    float acc[64];
#pragma unroll
    for (int o = 0; o < 64; o++) acc[o] = bv[og * 64 + o];

#pragma unroll 1
    for (int c0 = 0; c0 < C; c0 += 8) {
        float xr[8];
#pragma unroll
        for (int cc = 0; cc < 8; cc++) xr[cc] = xb[(size_t)(c0 + cc) * L];
#pragma unroll
        for (int o = 0; o < 64; o++) {
#pragma unroll
            for (int cc = 0; cc < 8; cc++)
                acc[o] = fmaf(W[o * C + c0 + cc], xr[cc], acc[o]);
        }
    }
    float* vp = vt + ((size_t)b * L + l) * C + og * 64;
#pragma unroll
    for (int o = 0; o < 64; o++) vp[o] = acc[o];
}

// One block per (i-tile of TI rows, batch b). Two-pass flash softmax.
__global__ __launch_bounds__(256) void attn_kernel(
    const float* __restrict__ x, const float* __restrict__ qt,
    const float* __restrict__ kk, const float* __restrict__ vt,
    const float* __restrict__ gamma_p, float* __restrict__ out)
{
    const int i0 = blockIdx.x * TI;
    const int b = blockIdx.y;
    const int t = threadIdx.x;
    const int wave = t >> 6;
    const int lane = t & 63;

    __shared__ float q_s[TI][CQK];       // 2 KB
    __shared__ float p_s[256][TI];       // 16 KB
    __shared__ float red_m[4][TI];
    __shared__ float red_l[4][TI];
    __shared__ float m_fin[TI];
    __shared__ float il_fin[TI];
    __shared__ float acc_s[TI][C];       // 16 KB

    // load Q tile (TI*CQK = 512 floats)
    {
        const float* qb = qt + ((size_t)b * L + i0) * CQK;
        ((float*)q_s)[t] = qb[t];
        ((float*)q_s)[t + 256] = qb[t + 256];
    }
    __syncthreads();

    const float* kb = kk + ((size_t)b * CQK) * L;

    // ---- Pass A: per-row max + exp-sum ----
    float m_r[TI], l_r[TI];
#pragma unroll
    for (int i = 0; i < TI; i++) { m_r[i] = -1e30f; l_r[i] = 0.0f; }

#pragma unroll 1
    for (int jt = 0; jt < L / 256; jt++) {
        const int j = jt * 256 + t;
        float k_r[CQK];
#pragma unroll
        for (int c = 0; c < CQK; c++) k_r[c] = kb[(size_t)c * L + j];
#pragma unroll
        for (int i = 0; i < TI; i++) {
            float s = 0.0f;
#pragma unroll
            for (int c = 0; c < CQK; c++) s = fmaf(q_s[i][c], k_r[c], s);
            const float mn = fmaxf(m_r[i], s);
            l_r[i] = l_r[i] * __expf(m_r[i] - mn) + __expf(s - mn);
            m_r[i] = mn;
        }
    }
    // wave-level (m,l) combine
#pragma unroll
    for (int i = 0; i < TI; i++) {
        float m = m_r[i], l = l_r[i];
#pragma unroll
        for (int off = 32; off >= 1; off >>= 1) {
            const float mo = __shfl_xor(m, off);
            const float lo = __shfl_xor(l, off);
            const float mn = fmaxf(m, mo);
            l = l * __expf(m - mn) + lo * __expf(mo - mn);
            m = mn;
        }
        if (lane == 0) { red_m[wave][i] = m; red_l[wave][i] = l; }
    }
    __syncthreads();
    if (t < TI) {
        float m = red_m[0][t], l = red_l[0][t];
#pragma unroll
        for (int w = 1; w < 4; w++) {
            const float mo = red_m[w][t], lo = red_l[w][t];
            const float mn = fmaxf(m, mo);
            l = l * __expf(m - mn) + lo * __expf(mo - mn);
            m = mn;
        }
        m_fin[t] = m;
        il_fin[t] = 1.0f / l;
    }
    __syncthreads();

    // ---- Pass B: recompute scores per j-tile, PV accumulate ----
    const float* vb = vt + ((size_t)b * L) * C;
    const int cbase = lane * 4;          // each lane owns a c-quad
    float acc_r[TI][4];
#pragma unroll
    for (int i = 0; i < TI; i++) {
#pragma unroll
        for (int cc = 0; cc < 4; cc++) acc_r[i][cc] = 0.0f;
    }

#pragma unroll 1
    for (int j0 = 0; j0 < L; j0 += 256) {
        const int j = j0 + t;
        float k_r[CQK];
#pragma unroll
        for (int c = 0; c < CQK; c++) k_r[c] = kb[(size_t)c * L + j];
        float p_r[TI];
#pragma unroll
        for (int i = 0; i < TI; i++) {
            float s = 0.0f;
#pragma unroll
            for (int c = 0; c < CQK; c++) s = fmaf(q_s[i][c], k_r[c], s);
            p_r[i] = __expf(s - m_fin[i]) * il_fin[i];
        }
        __syncthreads();   // previous tile's p_s fully consumed
#pragma unroll
        for (int q4 = 0; q4 < TI / 4; q4++)
            *(float4*)&p_s[t][q4 * 4] =
                make_float4(p_r[q4 * 4 + 0], p_r[q4 * 4 + 1],
                            p_r[q4 * 4 + 2], p_r[q4 * 4 + 3]);
        __syncthreads();

        // PV: waves split jj (disjoint), p reads are wave-uniform broadcasts
#pragma unroll 4
        for (int jj = wave; jj < 256; jj += 4) {
            const float4 vv = *(const float4*)&vb[(size_t)(j0 + jj) * C + cbase];
            const float vvf[4] = { vv.x, vv.y, vv.z, vv.w };
#pragma unroll
            for (int q4 = 0; q4 < TI / 4; q4++) {
                const float4 pp = *(const float4*)&p_s[jj][q4 * 4];
                const float ppf[4] = { pp.x, pp.y, pp.z, pp.w };
#pragma unroll
                for (int ii = 0; ii < 4; ii++) {
#pragma unroll
                    for (int cc = 0; cc < 4; cc++)
                        acc_r[q4 * 4 + ii][cc] =
                            fmaf(ppf[ii], vvf[cc], acc_r[q4 * 4 + ii][cc]);
                }
            }
        }
    }

    // cross-wave partial-sum reduce into acc_s
#pragma unroll
    for (int w = 0; w < 4; w++) {
        if (wave == w) {
#pragma unroll
            for (int i = 0; i < TI; i++) {
                float4* dst = (float4*)&acc_s[i][cbase];
                if (w == 0) {
                    *dst = make_float4(acc_r[i][0], acc_r[i][1],
                                       acc_r[i][2], acc_r[i][3]);
                } else {
                    float4 d = *dst;
                    d.x += acc_r[i][0]; d.y += acc_r[i][1];
                    d.z += acc_r[i][2]; d.w += acc_r[i][3];
                    *dst = d;
                }
            }
        }
        __syncthreads();
    }

    // epilogue: out = gamma*acc + x, i-contiguous 64B writes
    const float g = gamma_p[0];
    const int ii = t & 15;
    const int cg0 = t >> 4;
    const size_t base = (size_t)b * C * L + i0 + ii;
#pragma unroll
    for (int cc = 0; cc < 16; cc++) {
        const int c = cg0 * 16 + cc;
        const size_t idx = base + (size_t)c * L;
        out[idx] = g * acc_s[ii][c] + x[idx];
    }
}

extern "C" void kernel_launch(void* const* d_in, const int* in_sizes, int n_in,
                              void* d_out, int out_size, void* d_ws, size_t ws_size,
                              hipStream_t stream) {
    const float* x  = (const float*)d_in[0];
    const float* Wq = (const float*)d_in[1];
    const float* bq = (const float*)d_in[2];
    const float* Wk = (const float*)d_in[3];
    const float* bk = (const float*)d_in[4];
    const float* Wv = (const float*)d_in[5];
    const float* bv = (const float*)d_in[6];
    const float* gm = (const float*)d_in[7];
    float* out = (float*)d_out;

    float* qt = (float*)d_ws;                       // B*L*CQK
    float* kk = qt + (size_t)B * L * CQK;           // B*CQK*L
    float* vt = kk + (size_t)B * CQK * L;           // B*L*C  (needs 20 MB total)

    qk_proj<<<dim3(B, L / 256), 256, 0, stream>>>(x, Wq, bq, Wk, bk, qt, kk);
    v_proj<<<dim3(B, L / 64), 256, 0, stream>>>(x, Wv, bv, vt);
    attn_kernel<<<dim3(L / TI, B), 256, 0, stream>>>(x, qt, kk, vt, gm, out);
}

// Round 3
// 101.745 us; speedup vs baseline: 10.2576x; 10.2576x over previous
//
#include <hip/hip_runtime.h>

#define B 8
#define C 256
#define L 2048
#define CQK 32

typedef unsigned short u16;
typedef __attribute__((ext_vector_type(8))) short bf8;   // 8 bf16 = 4 VGPR
typedef __attribute__((ext_vector_type(4))) short s4v;   // 4 bf16 = 2 VGPR
typedef __attribute__((ext_vector_type(4))) float f4;    // mfma C/D

__device__ __forceinline__ u16 f2bf(float f) {
    union { float f; unsigned u; } v; v.f = f;
    unsigned r = v.u + 0x7FFFu + ((v.u >> 16) & 1u);   // RNE
    return (u16)(r >> 16);
}

__device__ __forceinline__ void gld16(const u16* gp, u16* lp) {
    auto* g1 = (const __attribute__((address_space(1))) u16*)gp;
    auto* l3 = (__attribute__((address_space(3))) u16*)lp;
    __builtin_amdgcn_global_load_lds(g1, l3, 16, 0, 0);
}

// ---------------------------------------------------------------------------
// wconv: W{q,k,v} fp32 -> Wall[320][256] bf16 ; biases -> ball[320] fp32
// rows 0-31 = Wq, 32-63 = Wk, 64-319 = Wv
// ---------------------------------------------------------------------------
__global__ __launch_bounds__(256) void wconv(
    const float* __restrict__ Wq, const float* __restrict__ bq,
    const float* __restrict__ Wk, const float* __restrict__ bk,
    const float* __restrict__ Wv, const float* __restrict__ bv,
    u16* __restrict__ Wall, float* __restrict__ ball)
{
    const int idx = (blockIdx.x * 256 + threadIdx.x) * 4;   // 80 blocks * 1024 = 81920
    const int row = idx >> 8, c = idx & 255;
    const float* s;
    if (row < 32)      s = Wq + row * C + c;
    else if (row < 64) s = Wk + (row - 32) * C + c;
    else               s = Wv + (row - 64) * C + c;
    const float4 v = *(const float4*)s;
    uint2 o;
    o.x = f2bf(v.x) | ((unsigned)f2bf(v.y) << 16);
    o.y = f2bf(v.z) | ((unsigned)f2bf(v.w) << 16);
    *(uint2*)(Wall + idx) = o;
    if (blockIdx.x == 0) {
        for (int i = threadIdx.x; i < 320; i += 256)
            ball[i] = (i < 32) ? bq[i] : (i < 64) ? bk[i - 32] : bv[i - 64];
    }
}

// ---------------------------------------------------------------------------
// xconv: x[b][c][l] fp32 -> xt[b][l][c] bf16 (LDS transpose)
// ---------------------------------------------------------------------------
__global__ __launch_bounds__(256) void xconv(const float* __restrict__ x,
                                             u16* __restrict__ xt)
{
    __shared__ float tile[64][65];
    const int b = blockIdx.z, c0 = blockIdx.y * 64, l0 = blockIdx.x * 64;
    const int t = threadIdx.x;
    const int ln = t & 63, w = t >> 6;
#pragma unroll
    for (int i = 0; i < 16; i++) {
        const int c = w * 16 + i;
        tile[c][ln] = x[((size_t)(b * C + c0 + c)) * L + l0 + ln];
    }
    __syncthreads();
    const int lrow = t >> 2, q = t & 3;
    unsigned o[8];
#pragma unroll
    for (int jj = 0; jj < 8; jj++) {
        const float a0 = tile[q * 16 + jj * 2][lrow];
        const float a1 = tile[q * 16 + jj * 2 + 1][lrow];
        o[jj] = f2bf(a0) | ((unsigned)f2bf(a1) << 16);
    }
    u16* dst = xt + ((size_t)(b * L + l0 + lrow)) * 256 + c0 + q * 16;
    *(uint4*)(dst)     = make_uint4(o[0], o[1], o[2], o[3]);
    *(uint4*)(dst + 8) = make_uint4(o[4], o[5], o[6], o[7]);
}

// ---------------------------------------------------------------------------
// proj: [320x256] x [256 x L] MFMA GEMM per batch.
//   qt[b][l][32], kt[b][l][32] (c contiguous), vv[b][c][l] (l contiguous)
// Block: 256 thr (4 waves), l-tile = 64. xt tile staged in LDS (xor-swizzled).
// ---------------------------------------------------------------------------
__global__ __launch_bounds__(256) void proj(
    const u16* __restrict__ xt, const u16* __restrict__ Wall,
    const float* __restrict__ ball, u16* __restrict__ qt,
    u16* __restrict__ kt, u16* __restrict__ vv)
{
    __shared__ u16 xlds[64 * 256];   // 32 KB, 512B rows, chunk-swizzled
    const int b = blockIdx.y, l0 = blockIdx.x * 64;
    const int t = threadIdx.x, w = t >> 6, ln = t & 63;
    const int lc = ln & 15, g = ln >> 4;

#pragma unroll
    for (int mm = 0; mm < 8; mm++) {
        const int cg = t + mm * 256;           // 16B-chunk index 0..2047
        const int lrow = cg >> 5, phys = cg & 31;
        const int logical = (phys & 24) | ((phys & 7) ^ (lrow & 7));
        gld16(xt + ((size_t)(b * L + l0 + lrow)) * 256 + logical * 8,
              xlds + (size_t)(w * 64 + mm * 256) * 8);
    }
    __syncthreads();

    f4 acc[5][4];
#pragma unroll
    for (int rt = 0; rt < 5; rt++) {
        const int row0 = (w * 5 + rt) * 16 + g * 4;
        const float4 bi = *(const float4*)(ball + row0);
#pragma unroll
        for (int ct = 0; ct < 4; ct++) {
            acc[rt][ct].x = bi.x; acc[rt][ct].y = bi.y;
            acc[rt][ct].z = bi.z; acc[rt][ct].w = bi.w;
        }
    }

#pragma unroll
    for (int k = 0; k < 8; k++) {
        bf8 bfr[4];
#pragma unroll
        for (int ct = 0; ct < 4; ct++) {
            const int lrow = ct * 16 + lc;
            const int lchunk = k * 4 + g;
            const int phys = (lchunk & 24) | ((lchunk & 7) ^ (lrow & 7));
            bfr[ct] = *(const bf8*)(xlds + (size_t)lrow * 256 + phys * 8);
        }
#pragma unroll
        for (int rt = 0; rt < 5; rt++) {
            const bf8 af = *(const bf8*)(Wall +
                (size_t)((w * 5 + rt) * 16 + lc) * 256 + k * 32 + g * 8);
#pragma unroll
            for (int ct = 0; ct < 4; ct++)
                acc[rt][ct] = __builtin_amdgcn_mfma_f32_16x16x32_bf16(
                    af, bfr[ct], acc[rt][ct], 0, 0, 0);
        }
    }

#pragma unroll
    for (int rt = 0; rt < 5; rt++) {
        const int rg = w * 5 + rt;
        const int row0 = rg * 16 + g * 4;
#pragma unroll
        for (int ct = 0; ct < 4; ct++) {
            const int l = l0 + ct * 16 + lc;
            const f4 a = acc[rt][ct];
            if (rg < 2) {
                uint2 o;
                o.x = f2bf(a.x) | ((unsigned)f2bf(a.y) << 16);
                o.y = f2bf(a.z) | ((unsigned)f2bf(a.w) << 16);
                *(uint2*)(qt + ((size_t)(b * L + l)) * 32 + row0) = o;
            } else if (rg < 4) {
                uint2 o;
                o.x = f2bf(a.x) | ((unsigned)f2bf(a.y) << 16);
                o.y = f2bf(a.z) | ((unsigned)f2bf(a.w) << 16);
                *(uint2*)(kt + ((size_t)(b * L + l)) * 32 + (row0 - 32)) = o;
            } else {
                const int c = row0 - 64;
                vv[((size_t)(b * C + c + 0)) * L + l] = f2bf(a.x);
                vv[((size_t)(b * C + c + 1)) * L + l] = f2bf(a.y);
                vv[((size_t)(b * C + c + 2)) * L + l] = f2bf(a.z);
                vv[((size_t)(b * C + c + 3)) * L + l] = f2bf(a.w);
            }
        }
    }
}

// ---------------------------------------------------------------------------
// attn: flash attention. Block = 4 waves, each wave owns 16 i-rows.
// j-step 32, double-buffered K/V staging via global_load_lds.
// S^T = mfma(K,Q): lane's softmax row = lc; PV: acc[16] 16x16 tiles.
// vs layout: [c 0..255][j 0..31] u16, row = 32 u16 = 64 B (4 chunks of 16 B).
// ---------------------------------------------------------------------------
__global__ __launch_bounds__(256) void attn(
    const u16* __restrict__ qt, const u16* __restrict__ kt,
    const u16* __restrict__ vv, const float* __restrict__ x,
    const float* __restrict__ gamma_p, float* __restrict__ out)
{
    __shared__ u16 vs[2][8192];    // [c][j] 64B rows
    __shared__ u16 ks[2][1024];    // chunk cseg*32+jr = K[j=jr][ch cseg*8..+8]
    __shared__ u16 ps[4][640];     // per-wave P: [i 0..15][j 0..31, pad to 40]
    const int b = blockIdx.y;
    const int t = threadIdx.x, w = t >> 6, ln = t & 63;
    const int lc = ln & 15, g = ln >> 4;
    const int i0 = blockIdx.x * 64 + w * 16;

    const bf8 qf = *(const bf8*)(qt + ((size_t)(b * L + i0 + lc)) * 32 + g * 8);
    u16* psw = ps[w];

    f4 acc[16];
    const f4 fz = {0.f, 0.f, 0.f, 0.f};
#pragma unroll
    for (int ct = 0; ct < 16; ct++) acc[ct] = fz;
    float m = -1e30f, lsum = 0.f;

    auto stage = [&](int buf, int j0) {
#pragma unroll
        for (int mm = 0; mm < 4; mm++) {
            const int cg = t + mm * 256;       // 16B chunk 0..1023
            const int c = cg >> 2, ch = cg & 3;
            gld16(vv + ((size_t)(b * C + c)) * L + j0 + ch * 8,
                  vs[buf] + (size_t)(w * 64 + mm * 256) * 8);
        }
        if (w < 2) {   // 128 chunks of K
            const int cseg = t >> 5, jr = t & 31;
            gld16(kt + ((size_t)(b * L + j0 + jr)) * 32 + cseg * 8,
                  ks[buf] + (size_t)(w * 64) * 8);
        }
    };

    stage(0, 0);
    __syncthreads();
    int cur = 0;

#pragma unroll 1
    for (int jt = 0; jt < L / 32; jt++) {
        if (jt < L / 32 - 1) stage(cur ^ 1, (jt + 1) * 32);

        f4 s4[2];
#pragma unroll
        for (int tt = 0; tt < 2; tt++) {
            const bf8 kf = *(const bf8*)(ks[cur] + (size_t)(g * 32 + tt * 16 + lc) * 8);
            s4[tt] = __builtin_amdgcn_mfma_f32_16x16x32_bf16(kf, qf, fz, 0, 0, 0);
        }
        // row (= lc) max over the 32 j of this tile
        float tm = fmaxf(fmaxf(fmaxf(s4[0].x, s4[0].y), fmaxf(s4[0].z, s4[0].w)),
                         fmaxf(fmaxf(s4[1].x, s4[1].y), fmaxf(s4[1].z, s4[1].w)));
        tm = fmaxf(tm, __shfl_xor(tm, 16));
        tm = fmaxf(tm, __shfl_xor(tm, 32));
        if (!__all(tm <= m + 8.f)) {           // defer-max (T13)
            const float mn = fmaxf(m, tm);
            const float scb = __expf(m - mn);
            const float f0 = __shfl(scb, g * 4 + 0), f1 = __shfl(scb, g * 4 + 1);
            const float f2 = __shfl(scb, g * 4 + 2), f3 = __shfl(scb, g * 4 + 3);
#pragma unroll
            for (int ct = 0; ct < 16; ct++) {
                acc[ct].x *= f0; acc[ct].y *= f1;
                acc[ct].z *= f2; acc[ct].w *= f3;
            }
            lsum *= scb; m = mn;
        }
        float psum = 0.f;
        s4v pw[2];
#pragma unroll
        for (int tt = 0; tt < 2; tt++) {
            const float p0 = __expf(s4[tt].x - m);
            const float p1 = __expf(s4[tt].y - m);
            const float p2 = __expf(s4[tt].z - m);
            const float p3 = __expf(s4[tt].w - m);
            psum += (p0 + p1) + (p2 + p3);
            s4v pv = {(short)f2bf(p0), (short)f2bf(p1),
                      (short)f2bf(p2), (short)f2bf(p3)};
            pw[tt] = pv;
        }
        psum += __shfl_xor(psum, 16);
        psum += __shfl_xor(psum, 32);
        lsum += psum;
#pragma unroll
        for (int tt = 0; tt < 2; tt++)
            *(s4v*)(psw + lc * 40 + tt * 16 + g * 4) = pw[tt];

        // P back as A-fragment: row=lc, j-chunk g*8..g*8+7
        const s4v plo = *(const s4v*)(psw + lc * 40 + g * 8);
        const s4v phi = *(const s4v*)(psw + lc * 40 + g * 8 + 4);
        const bf8 pa = __builtin_shufflevector(plo, phi, 0, 1, 2, 3, 4, 5, 6, 7);
#pragma unroll
        for (int ct = 0; ct < 16; ct++) {
            const bf8 vf = *(const bf8*)(vs[cur] + (size_t)(ct * 16 + lc) * 32 + g * 8);
            acc[ct] = __builtin_amdgcn_mfma_f32_16x16x32_bf16(pa, vf, acc[ct], 0, 0, 0);
        }
        __syncthreads();
        cur ^= 1;
    }

    const float il = 1.0f / lsum;
    const float f0 = __shfl(il, g * 4 + 0), f1 = __shfl(il, g * 4 + 1);
    const float f2 = __shfl(il, g * 4 + 2), f3 = __shfl(il, g * 4 + 3);
    const float gmm = gamma_p[0];
#pragma unroll
    for (int ct = 0; ct < 16; ct++) {
        const int c = ct * 16 + lc;
        const size_t adr = ((size_t)(b * C + c)) * L + i0 + g * 4;
        const float4 xv = *(const float4*)(x + adr);
        float4 o;
        o.x = gmm * acc[ct].x * f0 + xv.x;
        o.y = gmm * acc[ct].y * f1 + xv.y;
        o.z = gmm * acc[ct].z * f2 + xv.z;
        o.w = gmm * acc[ct].w * f3 + xv.w;
        *(float4*)(out + adr) = o;
    }
}

extern "C" void kernel_launch(void* const* d_in, const int* in_sizes, int n_in,
                              void* d_out, int out_size, void* d_ws, size_t ws_size,
                              hipStream_t stream) {
    const float* x  = (const float*)d_in[0];
    const float* Wq = (const float*)d_in[1];
    const float* bq = (const float*)d_in[2];
    const float* Wk = (const float*)d_in[3];
    const float* bk = (const float*)d_in[4];
    const float* Wv = (const float*)d_in[5];
    const float* bv = (const float*)d_in[6];
    const float* gm = (const float*)d_in[7];
    float* out = (float*)d_out;

    u16* xt   = (u16*)d_ws;                          // B*L*C       bf16 (8 MB)
    u16* vvp  = xt  + (size_t)B * L * C;             // B*C*L       bf16 (8 MB)
    u16* qtp  = vvp + (size_t)B * C * L;             // B*L*CQK     bf16 (256 KB)
    u16* ktp  = qtp + (size_t)B * L * CQK;           // B*L*CQK     bf16 (256 KB)
    u16* Wall = ktp + (size_t)B * L * CQK;           // 320*256     bf16 (160 KB)
    float* ball = (float*)(Wall + 320 * 256);        // 320         fp32

    wconv<<<80, 256, 0, stream>>>(Wq, bq, Wk, bk, Wv, bv, Wall, ball);
    xconv<<<dim3(L / 64, C / 64, B), 256, 0, stream>>>(x, xt);
    proj<<<dim3(L / 64, B), 256, 0, stream>>>(xt, Wall, ball, qtp, ktp, vvp);
    attn<<<dim3(L / 64, B), 256, 0, stream>>>(qtp, ktp, vvp, x, gm, out);
}